// Round 1
// baseline (23846.754 us; speedup 1.0000x reference)
//
#include <hip/hip_runtime.h>
#include <hip/hip_bf16.h>

#define B_   2
#define T_   2048
#define E_   1024
#define E3_  3072
#define H_   16
#define HD_  64
#define L_   8
#define V_   128
#define M_   (B_*T_)      // 4096 rows
#define EPS_ 1e-5f
#define QB_  128          // attention q-rows per block
#define KB_  32           // attention kv tile

// ---------------- embedding gather ----------------
__global__ __launch_bounds__(256) void embed_k(const int* __restrict__ tokens,
                                               const float* __restrict__ emb,
                                               float* __restrict__ x) {
    int row = blockIdx.x;                       // 0..M_-1
    int tok = tokens[row];
    const float4* s = (const float4*)(emb + (size_t)tok * E_);
    float4* d = (float4*)(x + (size_t)row * E_);
    d[threadIdx.x] = s[threadIdx.x];            // 256 thr * float4 = 1024 floats
}

// ---------------- fp32 tiled GEMM: C = A[M,K] @ W[K,N] + bias, opt ReLU ----
template<int BM, int BN, int BK, int TM, int TN, bool RELU>
__global__ __launch_bounds__((BM/TM)*(BN/TN)) void gemm_k(
        const float* __restrict__ A, const float* __restrict__ W,
        const float* __restrict__ bias, float* __restrict__ C,
        int M, int N, int K) {
    constexpr int THREADS = (BM/TM)*(BN/TN);
    constexpr int MG = TM/4;                    // 4-row groups (split tile)
    constexpr int NG = TN/4;
    __shared__ float As[BK][BM+4];
    __shared__ float Bs[BK][BN+4];
    const int t  = threadIdx.x;
    const int NT = BN/TN;
    const int tx = t % NT;
    const int ty = t / NT;
    const int brow = blockIdx.y * BM;
    const int bcol = blockIdx.x * BN;
    float acc[TM][TN] = {};

    constexpr int AP = (BM*BK/4)/THREADS;
    constexpr int BP = (BK*BN/4)/THREADS;

    for (int k0 = 0; k0 < K; k0 += BK) {
        #pragma unroll
        for (int p = 0; p < AP; ++p) {
            int idx = t + p*THREADS;
            int ar = idx / (BK/4);
            int ac = idx % (BK/4);
            float4 v = *(const float4*)(A + (size_t)(brow+ar)*K + k0 + ac*4);
            As[ac*4+0][ar] = v.x;
            As[ac*4+1][ar] = v.y;
            As[ac*4+2][ar] = v.z;
            As[ac*4+3][ar] = v.w;
        }
        #pragma unroll
        for (int p = 0; p < BP; ++p) {
            int idx = t + p*THREADS;
            int br = idx / (BN/4);
            int bc = idx % (BN/4);
            *(float4*)(&Bs[br][bc*4]) =
                *(const float4*)(W + (size_t)(k0+br)*N + bcol + bc*4);
        }
        __syncthreads();
        #pragma unroll
        for (int kk = 0; kk < BK; ++kk) {
            float a[TM], b[TN];
            #pragma unroll
            for (int g = 0; g < MG; ++g) {
                float4 v = *(const float4*)(&As[kk][g*(BM/MG) + ty*4]);
                a[g*4+0]=v.x; a[g*4+1]=v.y; a[g*4+2]=v.z; a[g*4+3]=v.w;
            }
            #pragma unroll
            for (int g = 0; g < NG; ++g) {
                float4 v = *(const float4*)(&Bs[kk][g*(BN/NG) + tx*4]);
                b[g*4+0]=v.x; b[g*4+1]=v.y; b[g*4+2]=v.z; b[g*4+3]=v.w;
            }
            #pragma unroll
            for (int i = 0; i < TM; ++i)
                #pragma unroll
                for (int j = 0; j < TN; ++j)
                    acc[i][j] = fmaf(a[i], b[j], acc[i][j]);
        }
        __syncthreads();
    }
    #pragma unroll
    for (int gi = 0; gi < MG; ++gi) {
        #pragma unroll
        for (int i = 0; i < 4; ++i) {
            int r = brow + gi*(BM/MG) + ty*4 + i;
            #pragma unroll
            for (int gj = 0; gj < NG; ++gj) {
                int c = bcol + gj*(BN/NG) + tx*4;
                float4 v;
                v.x = acc[gi*4+i][gj*4+0] + bias[c+0];
                v.y = acc[gi*4+i][gj*4+1] + bias[c+1];
                v.z = acc[gi*4+i][gj*4+2] + bias[c+2];
                v.w = acc[gi*4+i][gj*4+3] + bias[c+3];
                if (RELU) {
                    v.x = fmaxf(v.x, 0.f); v.y = fmaxf(v.y, 0.f);
                    v.z = fmaxf(v.z, 0.f); v.w = fmaxf(v.w, 0.f);
                }
                *(float4*)(&C[(size_t)r*N + c]) = v;
            }
        }
    }
}

// ---------------- attention (faithful masked softmax, full row) ------------
// Reference multiplies scores by tril mask BEFORE softmax: masked scores are
// exactly 0 and still participate in softmax AND in a@v. So we process ALL T
// keys; masked positions contribute score 0. Running max starts at 0 (the
// mask zeros are part of every row except the last one; pure scaling diff
// otherwise).
__global__ __launch_bounds__(QB_) void attn_k(const float* __restrict__ qkv,
                                              float* __restrict__ o) {
    const int bh = blockIdx.x;
    const int b = bh >> 4, h = bh & 15;
    const int qt = blockIdx.y * QB_ + threadIdx.x;   // query row in [0,T)
    const float* qkv_bh = qkv + (size_t)b*T_*E3_ + h*(3*HD_);
    float q[HD_];
    {
        const float* qr = qkv_bh + (size_t)qt*E3_;
        #pragma unroll
        for (int d = 0; d < HD_; d += 4) {
            float4 v = *(const float4*)(qr + d);
            q[d]=v.x; q[d+1]=v.y; q[d+2]=v.z; q[d+3]=v.w;
        }
    }
    float m = 0.f, Z = 0.f;
    float oa[HD_] = {};
    __shared__ float Ks[KB_][HD_];
    __shared__ float Vs[KB_][HD_];
    const float scale = 0.125f;   // 1/sqrt(64)

    for (int j0 = 0; j0 < T_; j0 += KB_) {
        __syncthreads();
        #pragma unroll
        for (int p = 0; p < (KB_*HD_/4)/QB_; ++p) {   // 4 float4 per thread
            int idx = threadIdx.x + p*QB_;
            int r = idx >> 4;                          // kv row in tile
            int c = idx & 15;                          // float4 within row
            const float* kr = qkv_bh + (size_t)(j0+r)*E3_ + HD_;
            *(float4*)(&Ks[r][c*4]) = *(const float4*)(kr + c*4);
            *(float4*)(&Vs[r][c*4]) = *(const float4*)(kr + HD_ + c*4);
        }
        __syncthreads();
        float s[KB_];
        #pragma unroll
        for (int jj = 0; jj < KB_; ++jj) {
            float a0=0.f, a1=0.f, a2=0.f, a3=0.f;
            #pragma unroll
            for (int d = 0; d < HD_; d += 4) {
                float4 kv = *(const float4*)(&Ks[jj][d]);
                a0 = fmaf(q[d+0], kv.x, a0);
                a1 = fmaf(q[d+1], kv.y, a1);
                a2 = fmaf(q[d+2], kv.z, a2);
                a3 = fmaf(q[d+3], kv.w, a3);
            }
            float sc = (a0+a1) + (a2+a3);
            s[jj] = (j0 + jj <= qt) ? sc * scale : 0.f;
        }
        float tm = m;
        #pragma unroll
        for (int jj = 0; jj < KB_; ++jj) tm = fmaxf(tm, s[jj]);
        float corr = __expf(m - tm);
        m = tm;
        Z *= corr;
        #pragma unroll
        for (int d = 0; d < HD_; ++d) oa[d] *= corr;
        #pragma unroll
        for (int jj = 0; jj < KB_; ++jj) {
            float w = __expf(s[jj] - m);
            Z += w;
            #pragma unroll
            for (int d = 0; d < HD_; d += 4) {
                float4 vv = *(const float4*)(&Vs[jj][d]);
                oa[d+0] = fmaf(w, vv.x, oa[d+0]);
                oa[d+1] = fmaf(w, vv.y, oa[d+1]);
                oa[d+2] = fmaf(w, vv.z, oa[d+2]);
                oa[d+3] = fmaf(w, vv.w, oa[d+3]);
            }
        }
    }
    float inv = 1.f / Z;
    float* orow = o + (size_t)(b*T_ + qt)*E_ + h*HD_;
    #pragma unroll
    for (int d = 0; d < HD_; d += 4) {
        float4 v = { oa[d]*inv, oa[d+1]*inv, oa[d+2]*inv, oa[d+3]*inv };
        *(float4*)(orow + d) = v;
    }
}

// ---------------- fused residual + layernorm: out = LN(a + res) -----------
__global__ __launch_bounds__(256) void ln_k(const float* __restrict__ a,
                                            const float* __restrict__ res,
                                            const float* __restrict__ g,
                                            const float* __restrict__ bi,
                                            float* __restrict__ out) {
    int row = blockIdx.x;
    int t = threadIdx.x;
    float4 va = ((const float4*)(a   + (size_t)row*E_))[t];
    float4 vb = ((const float4*)(res + (size_t)row*E_))[t];
    float x0 = va.x+vb.x, x1 = va.y+vb.y, x2 = va.z+vb.z, x3 = va.w+vb.w;
    float s  = x0+x1+x2+x3;
    float s2 = x0*x0 + x1*x1 + x2*x2 + x3*x3;
    #pragma unroll
    for (int off = 32; off > 0; off >>= 1) {
        s  += __shfl_down(s,  off);
        s2 += __shfl_down(s2, off);
    }
    __shared__ float red[8];
    int wave = t >> 6, lane = t & 63;
    if (lane == 0) { red[wave] = s; red[4+wave] = s2; }
    __syncthreads();
    float S  = red[0]+red[1]+red[2]+red[3];
    float S2 = red[4]+red[5]+red[6]+red[7];
    float mean = S * (1.f/E_);
    float var  = S2 * (1.f/E_) - mean*mean;
    float rstd = rsqrtf(var + EPS_);
    float4 vg  = ((const float4*)g)[t];
    float4 vbi = ((const float4*)bi)[t];
    float4 r;
    r.x = (x0-mean)*rstd*vg.x + vbi.x;
    r.y = (x1-mean)*rstd*vg.y + vbi.y;
    r.z = (x2-mean)*rstd*vg.z + vbi.z;
    r.w = (x3-mean)*rstd*vg.w + vbi.w;
    ((float4*)(out + (size_t)row*E_))[t] = r;
}

// ---------------- loss ----------------
__global__ void zero_k(float* p) { *p = 0.f; }

__global__ __launch_bounds__(V_) void loss_k(const float* __restrict__ logits,
                                             const int* __restrict__ targets,
                                             float* __restrict__ loss) {
    int row = blockIdx.x;
    int t = threadIdx.x;
    float x = logits[(size_t)row*V_ + t];
    float mx = x;
    #pragma unroll
    for (int off = 32; off > 0; off >>= 1) mx = fmaxf(mx, __shfl_down(mx, off));
    __shared__ float sh[4];
    int wave = t >> 6, lane = t & 63;
    if (!lane) sh[wave] = mx;
    __syncthreads();
    float Mx = fmaxf(sh[0], sh[1]);
    float e = __expf(x - Mx);
    float ssum = e;
    #pragma unroll
    for (int off = 32; off > 0; off >>= 1) ssum += __shfl_down(ssum, off);
    if (!lane) sh[2+wave] = ssum;
    __syncthreads();
    if (t == 0) {
        float Ssum = sh[2] + sh[3];
        float lse = Mx + logf(Ssum);
        float nll = lse - logits[(size_t)row*V_ + targets[row]];
        atomicAdd(loss, nll * (1.f/M_));
    }
}

// ---------------- launch ----------------
extern "C" void kernel_launch(void* const* d_in, const int* in_sizes, int n_in,
                              void* d_out, int out_size, void* d_ws, size_t ws_size,
                              hipStream_t stream) {
    const int*   tokens  = (const int*)d_in[0];
    const int*   targets = (const int*)d_in[1];
    const float* emb     = (const float*)d_in[2];
    const float* Wqkv    = (const float*)d_in[3];
    const float* bqkv    = (const float*)d_in[4];
    const float* aw1     = (const float*)d_in[5];
    const float* ab1     = (const float*)d_in[6];
    const float* aw2     = (const float*)d_in[7];
    const float* ab2     = (const float*)d_in[8];
    const float* ln1g    = (const float*)d_in[9];
    const float* ln1b    = (const float*)d_in[10];
    const float* fw1     = (const float*)d_in[11];
    const float* fb1     = (const float*)d_in[12];
    const float* fw2     = (const float*)d_in[13];
    const float* fb2     = (const float*)d_in[14];
    const float* ln2g    = (const float*)d_in[15];
    const float* ln2b    = (const float*)d_in[16];
    const float* headw   = (const float*)d_in[17];
    const float* headb   = (const float*)d_in[18];

    float* logits = (float*)d_out;
    float* loss   = logits + (size_t)M_*V_;

    float* ws = (float*)d_ws;
    const size_t SZ = (size_t)M_*E_;          // 4M floats
    float* x    = ws;                          // [M,E]
    float* qkv  = ws + SZ;                     // [M,3E] (3 slots)
    float* o    = ws + 4*SZ;                   // attn out / ffn2 out
    float* hbuf = ws + 5*SZ;                   // ffn hidden
    float* o2   = ws + 6*SZ;                   // attn-ffn out
    float* x1   = ws + 7*SZ;                   // post-LN1  (total 32M floats = 128MB)

    embed_k<<<M_, 256, 0, stream>>>(tokens, emb, x);

    for (int l = 0; l < L_; ++l) {
        gemm_k<128,128,16,8,8,false><<<dim3(E3_/128, M_/128), 256, 0, stream>>>(
            x, Wqkv + (size_t)l*E_*E3_, bqkv + (size_t)l*E3_, qkv, M_, E3_, E_);
        attn_k<<<dim3(B_*H_, T_/QB_), QB_, 0, stream>>>(qkv, o);
        gemm_k<128,128,16,8,8,true><<<dim3(E_/128, M_/128), 256, 0, stream>>>(
            o, aw1 + (size_t)l*E_*E_, ab1 + (size_t)l*E_, hbuf, M_, E_, E_);
        gemm_k<128,128,16,8,8,false><<<dim3(E_/128, M_/128), 256, 0, stream>>>(
            hbuf, aw2 + (size_t)l*E_*E_, ab2 + (size_t)l*E_, o2, M_, E_, E_);
        ln_k<<<M_, 256, 0, stream>>>(o2, x, ln1g + (size_t)l*E_, ln1b + (size_t)l*E_, x1);
        gemm_k<128,128,16,8,8,true><<<dim3(E_/128, M_/128), 256, 0, stream>>>(
            x1, fw1 + (size_t)l*E_*E_, fb1 + (size_t)l*E_, hbuf, M_, E_, E_);
        gemm_k<128,128,16,8,8,false><<<dim3(E_/128, M_/128), 256, 0, stream>>>(
            hbuf, fw2 + (size_t)l*E_*E_, fb2 + (size_t)l*E_, o, M_, E_, E_);
        ln_k<<<M_, 256, 0, stream>>>(x1, o, ln2g + (size_t)l*E_, ln2b + (size_t)l*E_, x);
    }

    // head GEMM: [M,E] @ [E,V] + bias -> logits (directly into d_out)
    gemm_k<64,128,16,4,8,false><<<dim3(V_/128, M_/64), 256, 0, stream>>>(
        x, headw, headb, logits, M_, V_, E_);

    zero_k<<<1, 1, 0, stream>>>(loss);
    loss_k<<<M_, V_, 0, stream>>>(logits, targets, loss);
}

// Round 2
// 5724.820 us; speedup vs baseline: 4.1655x; 4.1655x over previous
//
#include <hip/hip_runtime.h>
#include <hip/hip_bf16.h>

#define B_   2
#define T_   2048
#define E_   1024
#define E3_  3072
#define H_   16
#define HD_  64
#define L_   8
#define V_   128
#define M_   (B_*T_)
#define EPS_ 1e-5f

typedef __attribute__((ext_vector_type(8))) short bf16x8;
typedef __attribute__((ext_vector_type(8))) unsigned short us8;
typedef __attribute__((ext_vector_type(4))) float f32x4;

__device__ __forceinline__ float bf2f(unsigned short u) {
    union { unsigned int i; float f; } v; v.i = ((unsigned int)u) << 16; return v.f;
}
__device__ __forceinline__ unsigned short f2bf(float f) {
    unsigned int x = __float_as_uint(f);
    unsigned int r = (x + 0x7fffu + ((x >> 16) & 1u)) >> 16;
    return (unsigned short)r;
}

#if defined(__has_builtin)
#if __has_builtin(__builtin_amdgcn_global_load_lds)
#define HAVE_GLL 1
#endif
#endif

// ---------------- embedding gather: fp32 + bf16 ----------------
__global__ __launch_bounds__(256) void embed_k(const int* __restrict__ tokens,
                                               const float* __restrict__ emb,
                                               float* __restrict__ x,
                                               unsigned short* __restrict__ xb) {
    int row = blockIdx.x;
    int t = threadIdx.x;
    int tok = tokens[row];
    float4 v = ((const float4*)(emb + (size_t)tok * E_))[t];
    ((float4*)(x + (size_t)row * E_))[t] = v;
    ushort4 u;
    u.x = f2bf(v.x); u.y = f2bf(v.y); u.z = f2bf(v.z); u.w = f2bf(v.w);
    ((ushort4*)(xb + (size_t)row * E_))[t] = u;
}

// ---------------- transpose-cast: W[K][N] f32 -> Wt[N][K] bf16 ----------------
__global__ __launch_bounds__(256) void tcast_k(const float* __restrict__ W,
                                               unsigned short* __restrict__ Wt,
                                               int K, int N) {
    __shared__ float Ls[32][33];
    int k0 = blockIdx.x * 32, n0 = blockIdx.y * 32;
    int r = threadIdx.x >> 3, cq = threadIdx.x & 7;
    float4 v = *(const float4*)(W + (size_t)(k0 + r) * N + n0 + cq * 4);
    Ls[r][cq*4+0] = v.x; Ls[r][cq*4+1] = v.y; Ls[r][cq*4+2] = v.z; Ls[r][cq*4+3] = v.w;
    __syncthreads();
    ushort4 u;
    u.x = f2bf(Ls[cq*4+0][r]); u.y = f2bf(Ls[cq*4+1][r]);
    u.z = f2bf(Ls[cq*4+2][r]); u.w = f2bf(Ls[cq*4+3][r]);
    *(ushort4*)(Wt + (size_t)(n0 + r) * K + k0 + cq * 4) = u;
}

// ---------------- bf16 MFMA GEMM (m97 structure) ----------------
// C[M,N] = A[M,K]bf16 @ Bt[N,K]bf16^T + bias ; out fp32 or bf16, opt ReLU.
// 128x128 tile, BK=32, 4 waves (2x2 of 64x64), mfma_f32_16x16x32_bf16.
template<bool RELU, bool OUTBF>
__global__ __launch_bounds__(256) void mgemm_k(const unsigned short* __restrict__ A,
                                               const unsigned short* __restrict__ Bt,
                                               const float* __restrict__ bias,
                                               float* __restrict__ Cf,
                                               unsigned short* __restrict__ Cb,
                                               int N, int K) {
    __shared__ __attribute__((aligned(16))) unsigned short As[128 * 32];
    __shared__ __attribute__((aligned(16))) unsigned short Bs[128 * 32];
    const int t = threadIdx.x;
    const int w = t >> 6, l = t & 63;
    const int lr = l & 15, ls = l >> 4;
    const int brow = blockIdx.y * 128, bcol = blockIdx.x * 128;
    const int wr = (w >> 1) * 64, wc = (w & 1) * 64;

    f32x4 acc[4][4];
    const f32x4 fz = {0.f, 0.f, 0.f, 0.f};
    #pragma unroll
    for (int m = 0; m < 4; ++m)
        #pragma unroll
        for (int n = 0; n < 4; ++n) acc[m][n] = fz;

    for (int k0 = 0; k0 < K; k0 += 32) {
        __syncthreads();
        #pragma unroll
        for (int p = 0; p < 2; ++p) {
            int i = (w * 2 + p) * 64 + l;
            int row = i >> 2, kc = i & 3;
            const unsigned short* ga = A  + (size_t)(brow + row) * K + k0 + kc * 8;
            const unsigned short* gb = Bt + (size_t)(bcol + row) * K + k0 + kc * 8;
#ifdef HAVE_GLL
            __builtin_amdgcn_global_load_lds(
                (__attribute__((address_space(1))) void*)(void*)ga,
                (__attribute__((address_space(3))) void*)(void*)(As + (w * 2 + p) * 512),
                16, 0, 0);
            __builtin_amdgcn_global_load_lds(
                (__attribute__((address_space(1))) void*)(void*)gb,
                (__attribute__((address_space(3))) void*)(void*)(Bs + (w * 2 + p) * 512),
                16, 0, 0);
#else
            us8 ta = *(const us8*)ga;
            us8 tb = *(const us8*)gb;
            *(us8*)(As + (w * 2 + p) * 512 + l * 8) = ta;
            *(us8*)(Bs + (w * 2 + p) * 512 + l * 8) = tb;
#endif
        }
        __syncthreads();
        bf16x8 a[4], b[4];
        #pragma unroll
        for (int m = 0; m < 4; ++m)
            a[m] = *(const bf16x8*)(As + (wr + m * 16 + lr) * 32 + ls * 8);
        #pragma unroll
        for (int n = 0; n < 4; ++n)
            b[n] = *(const bf16x8*)(Bs + (wc + n * 16 + lr) * 32 + ls * 8);
        #pragma unroll
        for (int m = 0; m < 4; ++m)
            #pragma unroll
            for (int n = 0; n < 4; ++n)
                acc[m][n] = __builtin_amdgcn_mfma_f32_16x16x32_bf16(a[m], b[n], acc[m][n], 0, 0, 0);
    }

    #pragma unroll
    for (int m = 0; m < 4; ++m) {
        #pragma unroll
        for (int n = 0; n < 4; ++n) {
            #pragma unroll
            for (int r4 = 0; r4 < 4; ++r4) {
                int row = brow + wr + m * 16 + ls * 4 + r4;
                int col = bcol + wc + n * 16 + lr;
                float v = acc[m][n][r4] + bias[col];
                if (RELU) v = fmaxf(v, 0.f);
                if (OUTBF) Cb[(size_t)row * N + col] = f2bf(v);
                else       Cf[(size_t)row * N + col] = v;
            }
        }
    }
}

// ---------------- V suffix sums per (b,h): SufV[j] = sum_{i>=j} V[i] (bf16) --
__global__ __launch_bounds__(512) void sufv_k(const unsigned short* __restrict__ qkvb,
                                              unsigned short* __restrict__ SufV) {
    int bh = blockIdx.x;
    int c = threadIdx.x >> 6, d = threadIdx.x & 63;
    const unsigned short* vb = qkvb + (size_t)(bh >> 4) * T_ * E3_ + (bh & 15) * 192 + 128;
    __shared__ float csum[8][64];
    float acc = 0.f;
    for (int r = c * 256; r < c * 256 + 256; ++r)
        acc += bf2f(vb[(size_t)r * E3_ + d]);
    csum[c][d] = acc;
    __syncthreads();
    float run = 0.f;
    for (int cc = c + 1; cc < 8; ++cc) run += csum[cc][d];
    unsigned short* out = SufV + (size_t)bh * (T_ + 1) * HD_;
    if (c == 7) out[(size_t)T_ * HD_ + d] = 0;
    for (int r = c * 256 + 255; r >= c * 256; --r) {
        run += bf2f(vb[(size_t)r * E3_ + d]);
        out[(size_t)r * HD_ + d] = f2bf(run);
    }
}

// ---------------- attention: 4-lane groups, triangular + analytic masked tail
// Faithful semantics: masked scores are 0 (not -inf) pre-softmax. Keys j<=qt
// processed normally; keys j>qt contribute weight exp(-m) each and V-suffix-sum.
__global__ __launch_bounds__(256) void attn_k(const unsigned short* __restrict__ qkvb,
                                              const unsigned short* __restrict__ SufV,
                                              unsigned short* __restrict__ ob) {
    const int bh = blockIdx.x;
    const int b = bh >> 4, h = bh & 15;
    const int ytile = (gridDim.y - 1) - blockIdx.y;   // heavy blocks first
    const int t = threadIdx.x;
    const int g = t & 3, qr = t >> 2;
    const int qt = ytile * 64 + qr;
    const unsigned short* base = qkvb + (size_t)b * T_ * E3_ + h * 192;

    float q[16];
    {
        const unsigned short* qp = base + (size_t)qt * E3_ + g * 16;
        us8 u0 = *(const us8*)qp, u1 = *(const us8*)(qp + 8);
        #pragma unroll
        for (int j = 0; j < 8; ++j) { q[j] = bf2f(u0[j]); q[8 + j] = bf2f(u1[j]); }
    }

    __shared__ __attribute__((aligned(16))) float Ks[32][64];
    __shared__ __attribute__((aligned(16))) float Vs[32][64];

    float m = 0.f, Z = 0.f;
    float oa[16];
    #pragma unroll
    for (int j = 0; j < 16; ++j) oa[j] = 0.f;
    const float scale = 0.125f;
    const int jend = ytile * 64 + 64;

    for (int j0 = 0; j0 < jend; j0 += 32) {
        __syncthreads();
        #pragma unroll
        for (int p = 0; p < 2; ++p) {
            int idx = t + p * 256;
            int r = idx >> 4, c = idx & 15;
            const unsigned short* sp = base + (size_t)(j0 + r) * E3_ + 64 + c * 8;
            us8 u = *(const us8*)sp;
            float* dst = (c < 8) ? &Ks[r][c * 8] : &Vs[r][(c - 8) * 8];
            #pragma unroll
            for (int j = 0; j < 8; ++j) dst[j] = bf2f(u[j]);
        }
        __syncthreads();
        for (int jj = 0; jj < 32; jj += 4) {
            float pk[4];
            #pragma unroll
            for (int ky = 0; ky < 4; ++ky) {
                const float4* kr = (const float4*)&Ks[jj + ky][g * 16];
                float s0 = 0.f, s1 = 0.f, s2 = 0.f, s3 = 0.f;
                #pragma unroll
                for (int d4 = 0; d4 < 4; ++d4) {
                    float4 kv = kr[d4];
                    s0 = fmaf(q[d4*4+0], kv.x, s0);
                    s1 = fmaf(q[d4*4+1], kv.y, s1);
                    s2 = fmaf(q[d4*4+2], kv.z, s2);
                    s3 = fmaf(q[d4*4+3], kv.w, s3);
                }
                pk[ky] = (s0 + s1) + (s2 + s3);
            }
            #pragma unroll
            for (int off = 1; off < 4; off <<= 1) {
                #pragma unroll
                for (int ky = 0; ky < 4; ++ky)
                    pk[ky] += __shfl_xor(pk[ky], off);
            }
            float sc[4];
            #pragma unroll
            for (int ky = 0; ky < 4; ++ky)
                sc[ky] = (j0 + jj + ky <= qt) ? pk[ky] * scale : -1e30f;
            float nm = fmaxf(m, fmaxf(fmaxf(sc[0], sc[1]), fmaxf(sc[2], sc[3])));
            if (nm > m) {
                float corr = __expf(m - nm);
                Z *= corr;
                #pragma unroll
                for (int j = 0; j < 16; ++j) oa[j] *= corr;
                m = nm;
            }
            #pragma unroll
            for (int ky = 0; ky < 4; ++ky) {
                float wgt = __expf(sc[ky] - m);
                Z += wgt;
                const float4* vr = (const float4*)&Vs[jj + ky][g * 16];
                #pragma unroll
                for (int d4 = 0; d4 < 4; ++d4) {
                    float4 vv = vr[d4];
                    oa[d4*4+0] = fmaf(wgt, vv.x, oa[d4*4+0]);
                    oa[d4*4+1] = fmaf(wgt, vv.y, oa[d4*4+1]);
                    oa[d4*4+2] = fmaf(wgt, vv.z, oa[d4*4+2]);
                    oa[d4*4+3] = fmaf(wgt, vv.w, oa[d4*4+3]);
                }
            }
        }
    }
    // analytic masked tail: (T-1-qt) zero-scores, each weight exp(-m)
    float w0 = __expf(-m);
    Z += (float)(T_ - 1 - qt) * w0;
    {
        const unsigned short* sv = SufV + ((size_t)bh * (T_ + 1) + (qt + 1)) * HD_ + g * 16;
        us8 u0 = *(const us8*)sv, u1 = *(const us8*)(sv + 8);
        #pragma unroll
        for (int j = 0; j < 8; ++j) {
            oa[j]     = fmaf(w0, bf2f(u0[j]), oa[j]);
            oa[8 + j] = fmaf(w0, bf2f(u1[j]), oa[8 + j]);
        }
    }
    float inv = 1.f / Z;
    unsigned short* op = ob + (size_t)(b * T_ + qt) * E_ + h * HD_ + g * 16;
    #pragma unroll
    for (int j4 = 0; j4 < 4; ++j4) {
        ushort4 o4;
        o4.x = f2bf(oa[j4*4+0] * inv); o4.y = f2bf(oa[j4*4+1] * inv);
        o4.z = f2bf(oa[j4*4+2] * inv); o4.w = f2bf(oa[j4*4+3] * inv);
        ((ushort4*)op)[j4] = o4;
    }
}

// ---------------- fused residual + layernorm: out = LN(a + res), f32 + bf16 --
__global__ __launch_bounds__(256) void ln_k(const float* __restrict__ a,
                                            const float* __restrict__ res,
                                            const float* __restrict__ g,
                                            const float* __restrict__ bi,
                                            float* __restrict__ out,
                                            unsigned short* __restrict__ outb) {
    int row = blockIdx.x;
    int t = threadIdx.x;
    float4 va = ((const float4*)(a   + (size_t)row * E_))[t];
    float4 vb = ((const float4*)(res + (size_t)row * E_))[t];
    float x0 = va.x + vb.x, x1 = va.y + vb.y, x2 = va.z + vb.z, x3 = va.w + vb.w;
    float s  = x0 + x1 + x2 + x3;
    float s2 = x0*x0 + x1*x1 + x2*x2 + x3*x3;
    #pragma unroll
    for (int off = 32; off > 0; off >>= 1) {
        s  += __shfl_down(s,  off);
        s2 += __shfl_down(s2, off);
    }
    __shared__ float red[8];
    int wave = t >> 6, lane = t & 63;
    if (lane == 0) { red[wave] = s; red[4 + wave] = s2; }
    __syncthreads();
    float S  = red[0] + red[1] + red[2] + red[3];
    float S2 = red[4] + red[5] + red[6] + red[7];
    float mean = S * (1.f / E_);
    float var  = S2 * (1.f / E_) - mean * mean;
    float rstd = rsqrtf(var + EPS_);
    float4 vg  = ((const float4*)g)[t];
    float4 vbi = ((const float4*)bi)[t];
    float4 r;
    r.x = (x0 - mean) * rstd * vg.x + vbi.x;
    r.y = (x1 - mean) * rstd * vg.y + vbi.y;
    r.z = (x2 - mean) * rstd * vg.z + vbi.z;
    r.w = (x3 - mean) * rstd * vg.w + vbi.w;
    ((float4*)(out + (size_t)row * E_))[t] = r;
    ushort4 u;
    u.x = f2bf(r.x); u.y = f2bf(r.y); u.z = f2bf(r.z); u.w = f2bf(r.w);
    ((ushort4*)(outb + (size_t)row * E_))[t] = u;
}

// ---------------- loss ----------------
__global__ void zero_k(float* p) { *p = 0.f; }

__global__ __launch_bounds__(V_) void loss_k(const float* __restrict__ logits,
                                             const int* __restrict__ targets,
                                             float* __restrict__ loss) {
    int row = blockIdx.x;
    int t = threadIdx.x;
    float x = logits[(size_t)row * V_ + t];
    float mx = x;
    #pragma unroll
    for (int off = 32; off > 0; off >>= 1) mx = fmaxf(mx, __shfl_down(mx, off));
    __shared__ float sh[4];
    int wave = t >> 6, lane = t & 63;
    if (!lane) sh[wave] = mx;
    __syncthreads();
    float Mx = fmaxf(sh[0], sh[1]);
    float e = __expf(x - Mx);
    float ssum = e;
    #pragma unroll
    for (int off = 32; off > 0; off >>= 1) ssum += __shfl_down(ssum, off);
    if (!lane) sh[2 + wave] = ssum;
    __syncthreads();
    if (t == 0) {
        float Ssum = sh[2] + sh[3];
        float lse = Mx + logf(Ssum);
        float nll = lse - logits[(size_t)row * V_ + targets[row]];
        atomicAdd(loss, nll * (1.f / M_));
    }
}

// ---------------- launch ----------------
extern "C" void kernel_launch(void* const* d_in, const int* in_sizes, int n_in,
                              void* d_out, int out_size, void* d_ws, size_t ws_size,
                              hipStream_t stream) {
    const int*   tokens  = (const int*)d_in[0];
    const int*   targets = (const int*)d_in[1];
    const float* emb     = (const float*)d_in[2];
    const float* Wqkv    = (const float*)d_in[3];
    const float* bqkv    = (const float*)d_in[4];
    const float* aw1     = (const float*)d_in[5];
    const float* ab1     = (const float*)d_in[6];
    const float* aw2     = (const float*)d_in[7];
    const float* ab2     = (const float*)d_in[8];
    const float* ln1g    = (const float*)d_in[9];
    const float* ln1b    = (const float*)d_in[10];
    const float* fw1     = (const float*)d_in[11];
    const float* fb1     = (const float*)d_in[12];
    const float* fw2     = (const float*)d_in[13];
    const float* fb2     = (const float*)d_in[14];
    const float* ln2g    = (const float*)d_in[15];
    const float* ln2b    = (const float*)d_in[16];
    const float* headw   = (const float*)d_in[17];
    const float* headb   = (const float*)d_in[18];

    float* logits = (float*)d_out;
    float* loss   = logits + (size_t)M_ * V_;

    unsigned char* w8 = (unsigned char*)d_ws;
    float*          x    = (float*)(w8);                              // 16 MB
    float*          res  = (float*)(w8 + ((size_t)16  << 20));        // 16 MB
    float*          x1   = (float*)(w8 + ((size_t)32  << 20));        // 16 MB
    unsigned short* xb   = (unsigned short*)(w8 + ((size_t)48  << 20)); // 8 MB
    unsigned short* x1b  = (unsigned short*)(w8 + ((size_t)56  << 20)); // 8 MB
    unsigned short* ob   = (unsigned short*)(w8 + ((size_t)64  << 20)); // 8 MB
    unsigned short* hb   = (unsigned short*)(w8 + ((size_t)72  << 20)); // 8 MB
    unsigned short* qkvb = (unsigned short*)(w8 + ((size_t)80  << 20)); // 24 MB
    unsigned short* sufv = (unsigned short*)(w8 + ((size_t)104 << 20)); // 8.01 MB
    unsigned short* wt   = (unsigned short*)(w8 + ((size_t)113 << 20)); // 6 MB
    unsigned short* hwt  = (unsigned short*)(w8 + ((size_t)119 << 20)); // 0.25 MB

    embed_k<<<M_, 256, 0, stream>>>(tokens, emb, x, xb);

    for (int l = 0; l < L_; ++l) {
        tcast_k<<<dim3(E_/32, E3_/32), 256, 0, stream>>>(Wqkv + (size_t)l*E_*E3_, wt, E_, E3_);
        mgemm_k<false,true><<<dim3(E3_/128, M_/128), 256, 0, stream>>>(
            xb, wt, bqkv + (size_t)l*E3_, nullptr, qkvb, E3_, E_);
        sufv_k<<<B_*H_, 512, 0, stream>>>(qkvb, sufv);
        attn_k<<<dim3(B_*H_, T_/64), 256, 0, stream>>>(qkvb, sufv, ob);
        tcast_k<<<dim3(E_/32, E_/32), 256, 0, stream>>>(aw1 + (size_t)l*E_*E_, wt, E_, E_);
        mgemm_k<true,true><<<dim3(E_/128, M_/128), 256, 0, stream>>>(
            ob, wt, ab1 + (size_t)l*E_, nullptr, hb, E_, E_);
        tcast_k<<<dim3(E_/32, E_/32), 256, 0, stream>>>(aw2 + (size_t)l*E_*E_, wt, E_, E_);
        mgemm_k<false,false><<<dim3(E_/128, M_/128), 256, 0, stream>>>(
            hb, wt, ab2 + (size_t)l*E_, res, nullptr, E_, E_);
        ln_k<<<M_, 256, 0, stream>>>(res, x, ln1g + (size_t)l*E_, ln1b + (size_t)l*E_, x1, x1b);
        tcast_k<<<dim3(E_/32, E_/32), 256, 0, stream>>>(fw1 + (size_t)l*E_*E_, wt, E_, E_);
        mgemm_k<true,true><<<dim3(E_/128, M_/128), 256, 0, stream>>>(
            x1b, wt, fb1 + (size_t)l*E_, nullptr, hb, E_, E_);
        tcast_k<<<dim3(E_/32, E_/32), 256, 0, stream>>>(fw2 + (size_t)l*E_*E_, wt, E_, E_);
        mgemm_k<false,false><<<dim3(E_/128, M_/128), 256, 0, stream>>>(
            hb, wt, fb2 + (size_t)l*E_, res, nullptr, E_, E_);
        ln_k<<<M_, 256, 0, stream>>>(res, x1, ln2g + (size_t)l*E_, ln2b + (size_t)l*E_, x, xb);
    }

    tcast_k<<<dim3(E_/32, V_/32), 256, 0, stream>>>(headw, hwt, E_, V_);
    mgemm_k<false,false><<<dim3(V_/128, M_/128), 256, 0, stream>>>(
        xb, hwt, headb, logits, nullptr, V_, E_);

    zero_k<<<1, 1, 0, stream>>>(loss);
    loss_k<<<M_, V_, 0, stream>>>(logits, targets, loss);
}

// Round 3
// 3126.042 us; speedup vs baseline: 7.6284x; 1.8313x over previous
//
#include <hip/hip_runtime.h>
#include <hip/hip_bf16.h>

#define B_   2
#define T_   2048
#define E_   1024
#define E3_  3072
#define H_   16
#define HD_  64
#define L_   8
#define V_   128
#define M_   (B_*T_)
#define EPS_ 1e-5f
#define SUFP_ 2056   // padded row stride (u16) of suffix-V table

typedef __attribute__((ext_vector_type(8))) short bf16x8;
typedef __attribute__((ext_vector_type(8))) _Float16 f16x8;
typedef __attribute__((ext_vector_type(8))) unsigned short us8;
typedef __attribute__((ext_vector_type(4))) float f32x4;
typedef __attribute__((ext_vector_type(16))) float f32x16;

__device__ __forceinline__ float bf2f(unsigned short u) {
    union { unsigned int i; float f; } v; v.i = ((unsigned int)u) << 16; return v.f;
}
__device__ __forceinline__ unsigned short f2bf(float f) {
    unsigned int x = __float_as_uint(f);
    return (unsigned short)((x + 0x7fffu + ((x >> 16) & 1u)) >> 16);
}
__device__ __forceinline__ unsigned short f2hbits(float f) {
    union { _Float16 h; unsigned short u; } c; c.h = (_Float16)f; return c.u;
}
__device__ __forceinline__ float hbits2f(unsigned short u) {
    union { _Float16 h; unsigned short u; } c; c.u = u; return (float)c.h;
}

#if defined(__has_builtin)
#if __has_builtin(__builtin_amdgcn_global_load_lds)
#define HAVE_GLL 1
#endif
#endif

// ---------------- embedding gather: fp32 + bf16 ----------------
__global__ __launch_bounds__(256) void embed_k(const int* __restrict__ tokens,
                                               const float* __restrict__ emb,
                                               float* __restrict__ x,
                                               unsigned short* __restrict__ xb) {
    int row = blockIdx.x;
    int t = threadIdx.x;
    int tok = tokens[row];
    float4 v = ((const float4*)(emb + (size_t)tok * E_))[t];
    ((float4*)(x + (size_t)row * E_))[t] = v;
    ushort4 u;
    u.x = f2bf(v.x); u.y = f2bf(v.y); u.z = f2bf(v.z); u.w = f2bf(v.w);
    ((ushort4*)(xb + (size_t)row * E_))[t] = u;
}

// ---------------- transpose-cast: W[K][N] f32 -> Wt[N][K] bf16 ----------------
__global__ __launch_bounds__(256) void tcast_k(const float* __restrict__ W,
                                               unsigned short* __restrict__ Wt,
                                               int K, int N) {
    __shared__ float Ls[32][33];
    int k0 = blockIdx.x * 32, n0 = blockIdx.y * 32;
    int r = threadIdx.x >> 3, cq = threadIdx.x & 7;
    float4 v = *(const float4*)(W + (size_t)(k0 + r) * N + n0 + cq * 4);
    Ls[r][cq*4+0] = v.x; Ls[r][cq*4+1] = v.y; Ls[r][cq*4+2] = v.z; Ls[r][cq*4+3] = v.w;
    __syncthreads();
    ushort4 u;
    u.x = f2bf(Ls[cq*4+0][r]); u.y = f2bf(Ls[cq*4+1][r]);
    u.z = f2bf(Ls[cq*4+2][r]); u.w = f2bf(Ls[cq*4+3][r]);
    *(ushort4*)(Wt + (size_t)(n0 + r) * K + k0 + cq * 4) = u;
}

// ---------------- bf16 MFMA GEMM (m97 structure) ----------------
template<bool RELU, bool OUTBF>
__global__ __launch_bounds__(256) void mgemm_k(const unsigned short* __restrict__ A,
                                               const unsigned short* __restrict__ Bt,
                                               const float* __restrict__ bias,
                                               float* __restrict__ Cf,
                                               unsigned short* __restrict__ Cb,
                                               int N, int K) {
    __shared__ __attribute__((aligned(16))) unsigned short As[128 * 32];
    __shared__ __attribute__((aligned(16))) unsigned short Bs[128 * 32];
    const int t = threadIdx.x;
    const int w = t >> 6, l = t & 63;
    const int lr = l & 15, ls = l >> 4;
    const int brow = blockIdx.y * 128, bcol = blockIdx.x * 128;
    const int wr = (w >> 1) * 64, wc = (w & 1) * 64;

    f32x4 acc[4][4];
    const f32x4 fz = {0.f, 0.f, 0.f, 0.f};
    #pragma unroll
    for (int m = 0; m < 4; ++m)
        #pragma unroll
        for (int n = 0; n < 4; ++n) acc[m][n] = fz;

    for (int k0 = 0; k0 < K; k0 += 32) {
        __syncthreads();
        #pragma unroll
        for (int p = 0; p < 2; ++p) {
            int i = (w * 2 + p) * 64 + l;
            int row = i >> 2, kc = i & 3;
            const unsigned short* ga = A  + (size_t)(brow + row) * K + k0 + kc * 8;
            const unsigned short* gb = Bt + (size_t)(bcol + row) * K + k0 + kc * 8;
#ifdef HAVE_GLL
            __builtin_amdgcn_global_load_lds(
                (__attribute__((address_space(1))) void*)(void*)ga,
                (__attribute__((address_space(3))) void*)(void*)(As + (w * 2 + p) * 512),
                16, 0, 0);
            __builtin_amdgcn_global_load_lds(
                (__attribute__((address_space(1))) void*)(void*)gb,
                (__attribute__((address_space(3))) void*)(void*)(Bs + (w * 2 + p) * 512),
                16, 0, 0);
#else
            us8 ta = *(const us8*)ga;
            us8 tb = *(const us8*)gb;
            *(us8*)(As + (w * 2 + p) * 512 + l * 8) = ta;
            *(us8*)(Bs + (w * 2 + p) * 512 + l * 8) = tb;
#endif
        }
        __syncthreads();
        bf16x8 a[4], b[4];
        #pragma unroll
        for (int m = 0; m < 4; ++m)
            a[m] = *(const bf16x8*)(As + (wr + m * 16 + lr) * 32 + ls * 8);
        #pragma unroll
        for (int n = 0; n < 4; ++n)
            b[n] = *(const bf16x8*)(Bs + (wc + n * 16 + lr) * 32 + ls * 8);
        #pragma unroll
        for (int m = 0; m < 4; ++m)
            #pragma unroll
            for (int n = 0; n < 4; ++n)
                acc[m][n] = __builtin_amdgcn_mfma_f32_16x16x32_bf16(a[m], b[n], acc[m][n], 0, 0, 0);
    }

    #pragma unroll
    for (int m = 0; m < 4; ++m) {
        #pragma unroll
        for (int n = 0; n < 4; ++n) {
            #pragma unroll
            for (int r4 = 0; r4 < 4; ++r4) {
                int row = brow + wr + m * 16 + ls * 4 + r4;
                int col = bcol + wc + n * 16 + lr;
                float v = acc[m][n][r4] + bias[col];
                if (RELU) v = fmaxf(v, 0.f);
                if (OUTBF) Cb[(size_t)row * N + col] = f2bf(v);
                else       Cf[(size_t)row * N + col] = v;
            }
        }
    }
}

// ---------------- V transpose: qkvb V-region -> Vt[bh*64+d][T] fp16 ----------
__global__ __launch_bounds__(256) void vtrans_k(const unsigned short* __restrict__ qkvb,
                                                unsigned short* __restrict__ vt) {
    const int bh = blockIdx.x, b = bh >> 4, h = bh & 15;
    const int j0 = blockIdx.y * 64;
    const int t = threadIdx.x;
    __shared__ unsigned short tile[64][65];
    #pragma unroll
    for (int i = 0; i < 2; ++i) {
        int s = 2 * t + i;
        int key = s >> 3, c = s & 7;
        us8 v = *(const us8*)(qkvb + (size_t)(b * T_ + j0 + key) * E3_ + h * 192 + 128 + c * 8);
        #pragma unroll
        for (int j = 0; j < 8; ++j) tile[key][c * 8 + j] = f2hbits(bf2f(v[j]));
    }
    __syncthreads();
    #pragma unroll
    for (int i = 0; i < 2; ++i) {
        int s = 2 * t + i;
        int d = s >> 3, kc = s & 7;
        us8 o;
        #pragma unroll
        for (int j = 0; j < 8; ++j) o[j] = tile[kc * 8 + j][d];
        *(us8*)(vt + (size_t)(bh * 64 + d) * T_ + j0 + kc * 8) = o;
    }
}

// ---------------- suffix-V from vt: sufvT[row][k] = sum_{i>=k} V[i][d], fp16 --
__global__ __launch_bounds__(256) void sufv_k(const unsigned short* __restrict__ vt,
                                              unsigned short* __restrict__ sufvT) {
    const int t = threadIdx.x;
    const int rloc = t >> 3, seg = t & 7;
    const int row = blockIdx.x * 32 + rloc;
    const unsigned short* src = vt + (size_t)row * T_ + seg * 256;
    float part = 0.f;
    for (int c = 0; c < 32; ++c) {
        us8 v = ((const us8*)src)[c];
        #pragma unroll
        for (int j = 0; j < 8; ++j) part += hbits2f(v[j]);
    }
    __shared__ float ps[32][8];
    ps[rloc][seg] = part;
    __syncthreads();
    float run = 0.f;
    for (int s2 = seg + 1; s2 < 8; ++s2) run += ps[rloc][s2];
    unsigned short* dst = sufvT + (size_t)row * SUFP_ + seg * 256;
    if (seg == 7) sufvT[(size_t)row * SUFP_ + T_] = 0;
    for (int c = 31; c >= 0; --c) {
        us8 v = ((const us8*)src)[c];
        float s8 = run;
        us8 o;
        #pragma unroll
        for (int j = 7; j >= 0; --j) {
            s8 = hbits2f(v[j]) + s8;
            o[j] = f2hbits(s8);
        }
        run = s8;
        *(us8*)(dst + c * 8) = o;
    }
}

// ---------------- MFMA flash attention (faithful 0-mask semantics) ----------
// Fixed shift M0=8: p = exp(s-8); masked keys analytically: Z += (T-1-qt)*e^-8,
// O += e^-8 * SufV[qt+1]. 4 waves x 32 q-rows; KV step 64 (2 sub-tiles of 32).
__global__ __launch_bounds__(256) void attn_k(const unsigned short* __restrict__ qkvb,
                                              const unsigned short* __restrict__ sufvT,
                                              const unsigned short* __restrict__ vt,
                                              unsigned short* __restrict__ ob) {
    __shared__ __attribute__((aligned(16))) unsigned short Kl[64 * 64];  // swizzled bf16
    __shared__ __attribute__((aligned(16))) unsigned short Vl[64 * 72];  // fp16, padded
    const int bh = blockIdx.x, b = bh >> 4, h = bh & 15;
    const int ytile = (gridDim.y - 1) - blockIdx.y;       // heavy blocks first
    const int Q0 = ytile * 128;
    const int t = threadIdx.x, w = t >> 6, l = t & 63;
    const int lq = l & 31, h2 = l >> 5;
    const int q0w = Q0 + 32 * w;
    const unsigned short* qbase = qkvb + (size_t)b * T_ * E3_ + h * 192;

    // Q fragments: lane needs Q[q0w+lq][16c + 8*h2 + j]
    bf16x8 qf[4];
    #pragma unroll
    for (int c = 0; c < 4; ++c)
        qf[c] = *(const bf16x8*)(qbase + (size_t)(q0w + lq) * E3_ + c * 16 + h2 * 8);

    f32x16 o0, o1;
    #pragma unroll
    for (int i = 0; i < 16; ++i) { o0[i] = 0.f; o1[i] = 0.f; }
    float Zl = 0.f;

    for (int j0 = 0; j0 <= Q0 + 64; j0 += 64) {
        __syncthreads();
        // stage K (64 keys x 64 dims bf16), XOR-swizzled on 16B chunks
        #pragma unroll
        for (int i = 0; i < 2; ++i) {
            int s = 2 * t + i;
            int row = s >> 3, cc = s & 7;
            us8 kv = *(const us8*)(qbase + (size_t)(j0 + row) * E3_ + 64 + ((cc ^ (row & 7)) * 8));
            *(us8*)(Kl + row * 64 + cc * 8) = kv;
        }
        // stage Vt (64 dims x 64 keys fp16), row stride 72
        #pragma unroll
        for (int i = 0; i < 2; ++i) {
            int s = 2 * t + i;
            int d = s >> 3, kc = s & 7;
            us8 vv = *(const us8*)(vt + (size_t)(bh * 64 + d) * T_ + j0 + kc * 8);
            *(us8*)(Vl + d * 72 + kc * 8) = vv;
        }
        __syncthreads();

        #pragma unroll
        for (int ks = 0; ks < 2; ++ks) {
            const int kb0 = j0 + 32 * ks;
            if (kb0 > q0w) continue;                       // fully masked (tail covers)
            // QK^T: St[32k][32q] = K_tile @ Q^T, 4 dim-chunks
            f32x16 st;
            #pragma unroll
            for (int i = 0; i < 16; ++i) st[i] = 0.f;
            const int krow = 32 * ks + lq;
            #pragma unroll
            for (int c = 0; c < 4; ++c) {
                bf16x8 ka = *(const bf16x8*)(Kl + krow * 64 + (((2 * c + h2) ^ (krow & 7)) * 8));
                st = __builtin_amdgcn_mfma_f32_32x32x16_bf16(ka, qf[c], st, 0, 0, 0);
            }
            const bool diag = (kb0 == q0w);
            float p[16];
            #pragma unroll
            for (int r = 0; r < 16; ++r) {
                int kl = (r & 3) + 8 * (r >> 2) + 4 * h2;  // key-local index
                float e = __expf(st[r] * 0.125f - 8.0f);
                p[r] = (diag && (kl > lq)) ? 0.f : e;
                Zl += p[r];
            }
            unsigned short pb[16];
            #pragma unroll
            for (int r = 0; r < 16; ++r) pb[r] = f2hbits(p[r]);
            // exchange halves + PV
            #pragma unroll
            for (int sp = 0; sp < 2; ++sp) {
                int sb = 8 * sp + 4 * (1 - h2);            // regs to send
                int kb_ = 8 * sp + 4 * h2;                 // regs to keep
                unsigned int snd0 = (unsigned int)pb[sb]     | ((unsigned int)pb[sb+1] << 16);
                unsigned int snd1 = (unsigned int)pb[sb+2]   | ((unsigned int)pb[sb+3] << 16);
                unsigned int rc0 = (unsigned int)__shfl_xor((int)snd0, 32, 64);
                unsigned int rc1 = (unsigned int)__shfl_xor((int)snd1, 32, 64);
                unsigned int ow0 = (unsigned int)pb[kb_]     | ((unsigned int)pb[kb_+1] << 16);
                unsigned int ow1 = (unsigned int)pb[kb_+2]   | ((unsigned int)pb[kb_+3] << 16);
                union { unsigned int u[4]; f16x8 v; } pa;
                if (h2 == 0) { pa.u[0] = ow0; pa.u[1] = ow1; pa.u[2] = rc0; pa.u[3] = rc1; }
                else         { pa.u[0] = rc0; pa.u[1] = rc1; pa.u[2] = ow0; pa.u[3] = ow1; }
                const int kb = 2 * ks + sp;                // 16-key group within step
                f16x8 vb0 = *(const f16x8*)(Vl + (0  + lq) * 72 + kb * 16 + h2 * 8);
                f16x8 vb1 = *(const f16x8*)(Vl + (32 + lq) * 72 + kb * 16 + h2 * 8);
                o0 = __builtin_amdgcn_mfma_f32_32x32x16_f16(pa.v, vb0, o0, 0, 0, 0);
                o1 = __builtin_amdgcn_mfma_f32_32x32x16_f16(pa.v, vb1, o1, 0, 0, 0);
            }
        }
    }

    // finalize: Z across halves + analytic masked tail, then normalize + SufV
    float Zt = Zl + __shfl_xor(Zl, 32, 64);
    const float w0 = __expf(-8.0f);
    float Zf = Zt + (float)(T_ - 1 - (q0w + lq)) * w0;
    float zinv_own = 1.0f / Zf;
    #pragma unroll
    for (int r = 0; r < 16; ++r) {
        int m = (r & 3) + 8 * (r >> 2) + 4 * h2;           // q-local row
        float zq = __shfl(zinv_own, m, 64);
        int qg = q0w + m;
        float sv0 = hbits2f(sufvT[(size_t)(bh * 64 + lq)      * SUFP_ + qg + 1]);
        float sv1 = hbits2f(sufvT[(size_t)(bh * 64 + 32 + lq) * SUFP_ + qg + 1]);
        float v0 = (o0[r] + w0 * sv0) * zq;
        float v1 = (o1[r] + w0 * sv1) * zq;
        ob[(size_t)(b * T_ + qg) * E_ + h * 64 + lq]      = f2bf(v0);
        ob[(size_t)(b * T_ + qg) * E_ + h * 64 + 32 + lq] = f2bf(v1);
    }
}

// ---------------- fused residual + layernorm: out = LN(a + res), f32 + bf16 --
__global__ __launch_bounds__(256) void ln_k(const float* __restrict__ a,
                                            const float* __restrict__ res,
                                            const float* __restrict__ g,
                                            const float* __restrict__ bi,
                                            float* __restrict__ out,
                                            unsigned short* __restrict__ outb) {
    int row = blockIdx.x;
    int t = threadIdx.x;
    float4 va = ((const float4*)(a   + (size_t)row * E_))[t];
    float4 vb = ((const float4*)(res + (size_t)row * E_))[t];
    float x0 = va.x + vb.x, x1 = va.y + vb.y, x2 = va.z + vb.z, x3 = va.w + vb.w;
    float s  = x0 + x1 + x2 + x3;
    float s2 = x0*x0 + x1*x1 + x2*x2 + x3*x3;
    #pragma unroll
    for (int off = 32; off > 0; off >>= 1) {
        s  += __shfl_down(s,  off);
        s2 += __shfl_down(s2, off);
    }
    __shared__ float red[8];
    int wave = t >> 6, lane = t & 63;
    if (lane == 0) { red[wave] = s; red[4 + wave] = s2; }
    __syncthreads();
    float S  = red[0] + red[1] + red[2] + red[3];
    float S2 = red[4] + red[5] + red[6] + red[7];
    float mean = S * (1.f / E_);
    float var  = S2 * (1.f / E_) - mean * mean;
    float rstd = rsqrtf(var + EPS_);
    float4 vg  = ((const float4*)g)[t];
    float4 vbi = ((const float4*)bi)[t];
    float4 r;
    r.x = (x0 - mean) * rstd * vg.x + vbi.x;
    r.y = (x1 - mean) * rstd * vg.y + vbi.y;
    r.z = (x2 - mean) * rstd * vg.z + vbi.z;
    r.w = (x3 - mean) * rstd * vg.w + vbi.w;
    ((float4*)(out + (size_t)row * E_))[t] = r;
    ushort4 u;
    u.x = f2bf(r.x); u.y = f2bf(r.y); u.z = f2bf(r.z); u.w = f2bf(r.w);
    ((ushort4*)(outb + (size_t)row * E_))[t] = u;
}

// ---------------- loss ----------------
__global__ void zero_k(float* p) { *p = 0.f; }

__global__ __launch_bounds__(V_) void loss_k(const float* __restrict__ logits,
                                             const int* __restrict__ targets,
                                             float* __restrict__ loss) {
    int row = blockIdx.x;
    int t = threadIdx.x;
    float x = logits[(size_t)row * V_ + t];
    float mx = x;
    #pragma unroll
    for (int off = 32; off > 0; off >>= 1) mx = fmaxf(mx, __shfl_down(mx, off));
    __shared__ float sh[4];
    int wave = t >> 6, lane = t & 63;
    if (!lane) sh[wave] = mx;
    __syncthreads();
    float Mx = fmaxf(sh[0], sh[1]);
    float e = __expf(x - Mx);
    float ssum = e;
    #pragma unroll
    for (int off = 32; off > 0; off >>= 1) ssum += __shfl_down(ssum, off);
    if (!lane) sh[2 + wave] = ssum;
    __syncthreads();
    if (t == 0) {
        float Ssum = sh[2] + sh[3];
        float lse = Mx + logf(Ssum);
        float nll = lse - logits[(size_t)row * V_ + targets[row]];
        atomicAdd(loss, nll * (1.f / M_));
    }
}

// ---------------- launch ----------------
extern "C" void kernel_launch(void* const* d_in, const int* in_sizes, int n_in,
                              void* d_out, int out_size, void* d_ws, size_t ws_size,
                              hipStream_t stream) {
    const int*   tokens  = (const int*)d_in[0];
    const int*   targets = (const int*)d_in[1];
    const float* emb     = (const float*)d_in[2];
    const float* Wqkv    = (const float*)d_in[3];
    const float* bqkv    = (const float*)d_in[4];
    const float* aw1     = (const float*)d_in[5];
    const float* ab1     = (const float*)d_in[6];
    const float* aw2     = (const float*)d_in[7];
    const float* ab2     = (const float*)d_in[8];
    const float* ln1g    = (const float*)d_in[9];
    const float* ln1b    = (const float*)d_in[10];
    const float* fw1     = (const float*)d_in[11];
    const float* fb1     = (const float*)d_in[12];
    const float* fw2     = (const float*)d_in[13];
    const float* fb2     = (const float*)d_in[14];
    const float* ln2g    = (const float*)d_in[15];
    const float* ln2b    = (const float*)d_in[16];
    const float* headw   = (const float*)d_in[17];
    const float* headb   = (const float*)d_in[18];

    float* logits = (float*)d_out;
    float* loss   = logits + (size_t)M_ * V_;

    unsigned char* w8 = (unsigned char*)d_ws;
    float*          x    = (float*)(w8);                                // 16 MB
    float*          res  = (float*)(w8 + ((size_t)16  << 20));          // 16 MB
    float*          x1   = (float*)(w8 + ((size_t)32  << 20));          // 16 MB
    unsigned short* xb   = (unsigned short*)(w8 + ((size_t)48  << 20)); // 8 MB
    unsigned short* x1b  = (unsigned short*)(w8 + ((size_t)56  << 20)); // 8 MB
    unsigned short* ob   = (unsigned short*)(w8 + ((size_t)64  << 20)); // 8 MB
    unsigned short* hb   = (unsigned short*)(w8 + ((size_t)72  << 20)); // 8 MB
    unsigned short* qkvb = (unsigned short*)(w8 + ((size_t)80  << 20)); // 24 MB
    unsigned short* sufv = (unsigned short*)(w8 + ((size_t)104 << 20)); // 8.03 MB
    unsigned short* wt   = (unsigned short*)(w8 + ((size_t)113 << 20)); // 6 MB
    unsigned short* hwt  = (unsigned short*)(w8 + ((size_t)119 << 20)); // 0.25 MB
    unsigned short* vt   = (unsigned short*)(w8 + ((size_t)120 << 20)); // 8 MB

    embed_k<<<M_, 256, 0, stream>>>(tokens, emb, x, xb);

    for (int l = 0; l < L_; ++l) {
        tcast_k<<<dim3(E_/32, E3_/32), 256, 0, stream>>>(Wqkv + (size_t)l*E_*E3_, wt, E_, E3_);
        mgemm_k<false,true><<<dim3(E3_/128, M_/128), 256, 0, stream>>>(
            xb, wt, bqkv + (size_t)l*E3_, nullptr, qkvb, E3_, E_);
        vtrans_k<<<dim3(B_*H_, T_/64), 256, 0, stream>>>(qkvb, vt);
        sufv_k<<<(B_*H_*HD_)/32, 256, 0, stream>>>(vt, sufv);
        attn_k<<<dim3(B_*H_, T_/128), 256, 0, stream>>>(qkvb, sufv, vt, ob);
        tcast_k<<<dim3(E_/32, E_/32), 256, 0, stream>>>(aw1 + (size_t)l*E_*E_, wt, E_, E_);
        mgemm_k<true,true><<<dim3(E_/128, M_/128), 256, 0, stream>>>(
            ob, wt, ab1 + (size_t)l*E_, nullptr, hb, E_, E_);
        tcast_k<<<dim3(E_/32, E_/32), 256, 0, stream>>>(aw2 + (size_t)l*E_*E_, wt, E_, E_);
        mgemm_k<false,false><<<dim3(E_/128, M_/128), 256, 0, stream>>>(
            hb, wt, ab2 + (size_t)l*E_, res, nullptr, E_, E_);
        ln_k<<<M_, 256, 0, stream>>>(res, x, ln1g + (size_t)l*E_, ln1b + (size_t)l*E_, x1, x1b);
        tcast_k<<<dim3(E_/32, E_/32), 256, 0, stream>>>(fw1 + (size_t)l*E_*E_, wt, E_, E_);
        mgemm_k<true,true><<<dim3(E_/128, M_/128), 256, 0, stream>>>(
            x1b, wt, fb1 + (size_t)l*E_, nullptr, hb, E_, E_);
        tcast_k<<<dim3(E_/32, E_/32), 256, 0, stream>>>(fw2 + (size_t)l*E_*E_, wt, E_, E_);
        mgemm_k<false,false><<<dim3(E_/128, M_/128), 256, 0, stream>>>(
            hb, wt, fb2 + (size_t)l*E_, res, nullptr, E_, E_);
        ln_k<<<M_, 256, 0, stream>>>(res, x1, ln2g + (size_t)l*E_, ln2b + (size_t)l*E_, x, xb);
    }

    tcast_k<<<dim3(E_/32, V_/32), 256, 0, stream>>>(headw, hwt, E_, V_);
    mgemm_k<false,false><<<dim3(V_/128, M_/128), 256, 0, stream>>>(
        xb, hwt, headb, logits, nullptr, V_, E_);

    zero_k<<<1, 1, 0, stream>>>(loss);
    loss_k<<<M_, V_, 0, stream>>>(logits, targets, loss);
}